// Round 11
// baseline (270.927 us; speedup 1.0000x reference)
//
#include <hip/hip_runtime.h>
#include <hip/hip_bf16.h>
#include <math.h>

#define B_DIM 4
#define C_DIM 512
#define T_DIM 2048
#define H_DIM 8
#define OC3   1536
#define VN_STRIDE 2064   // R8-measured-best strides (R10 de-alias experiment regressed)
#define SCALE 0.044194173824159216f   // 512^-0.5 (full C, per reference)
// scale * log2(e): Q pre-scaled so softmax uses v_exp_f32 (exp2) directly
#define SCALE2 (0.044194173824159216f * 1.4426950408889634f)

typedef unsigned short ushortT;
typedef unsigned int uintT;
typedef __attribute__((ext_vector_type(8))) short bf16x8;
typedef __attribute__((ext_vector_type(4))) short bf16x4;
typedef __attribute__((ext_vector_type(4))) float f32x4;

__device__ __forceinline__ ushortT f2bf(float f) {
    union { float f; uintT u; } v; v.f = f;
    uintT r = v.u + 0x7FFF + ((v.u >> 16) & 1);   // RNE
    return (ushortT)(r >> 16);
}
__device__ __forceinline__ float bf2f(ushortT h) {
    union { uintT u; float f; } v; v.u = ((uintT)h) << 16;
    return v.f;
}
// pack two floats to packed bf16 pair, round-half-up
__device__ __forceinline__ uintT pack2bf(float a, float b) {
    uintT ua = __float_as_uint(a) + 0x8000u;
    uintT ub = __float_as_uint(b) + 0x8000u;
    return (ua >> 16) | (ub & 0xFFFF0000u);
}

// ---------------------------------------------------------------------------
// prep: fused conv_x (blocks 0..1023) + conv_w (blocks 1024..2047).
// ---------------------------------------------------------------------------
__global__ __launch_bounds__(256) void prep(const float* __restrict__ x,
                                            const float* __restrict__ qw,
                                            const float* __restrict__ pw,
                                            ushortT* __restrict__ xb,
                                            ushortT* __restrict__ qwb,
                                            ushortT* __restrict__ pwb) {
    __shared__ float xs[64][65];
    const int tid = threadIdx.x;
    const int blk = blockIdx.x;
    if (blk >= 1024) {   // ---- weight conversion ----
        int idx = ((blk - 1024) * 256 + tid) * 4;
        if (idx < OC3 * C_DIM) {
            float4 v = *(const float4*)(qw + idx);
            qwb[idx + 0] = f2bf(v.x); qwb[idx + 1] = f2bf(v.y);
            qwb[idx + 2] = f2bf(v.z); qwb[idx + 3] = f2bf(v.w);
        } else {
            idx -= OC3 * C_DIM;
            float4 v = *(const float4*)(pw + idx);
            pwb[idx + 0] = f2bf(v.x); pwb[idx + 1] = f2bf(v.y);
            pwb[idx + 2] = f2bf(v.z); pwb[idx + 3] = f2bf(v.w);
        }
        return;
    }
    // ---- x transpose ----
    const int b = blk >> 8, rem = blk & 255;
    const int c0 = (rem >> 5) * 64, t0 = (rem & 31) * 64;
    #pragma unroll
    for (int it = 0; it < 4; ++it) {
        int idx = it * 256 + tid;
        int r = idx >> 4, ch = idx & 15;
        float4 v = *(const float4*)(x + ((size_t)(b * C_DIM + c0 + r)) * T_DIM + t0 + ch * 4);
        xs[r][ch * 4 + 0] = v.x; xs[r][ch * 4 + 1] = v.y;
        xs[r][ch * 4 + 2] = v.z; xs[r][ch * 4 + 3] = v.w;
    }
    __syncthreads();
    #pragma unroll
    for (int it = 0; it < 2; ++it) {
        int idx = it * 256 + tid;
        int rt = idx >> 3, ch = idx & 7;
        union { ushortT s[8]; uint4 v; } tmp;
        #pragma unroll
        for (int k = 0; k < 8; ++k) tmp.s[k] = f2bf(xs[ch * 8 + k][rt]);
        *(uint4*)(xb + ((size_t)b * T_DIM + t0 + rt) * C_DIM + c0 + ch * 8) = tmp.v;
    }
}

// ---------------------------------------------------------------------------
// QKV GEMM: qkvT[m][o] = sum_c xb[m][c]*W[o][c] + bias[o]; Q scaled by SCALE2.
// V region (o>=1024) written transposed into Vn[b][h][d][VN_STRIDE-padded t].
// ---------------------------------------------------------------------------
__global__ __launch_bounds__(256, 2) void gemm_qkv(const ushortT* __restrict__ A,
                                                   const ushortT* __restrict__ Bw,
                                                   const float* __restrict__ bias,
                                                   ushortT* __restrict__ out,
                                                   ushortT* __restrict__ Vn) {
    __shared__ ushortT As[4096], Bs[4096];   // [128][32] swizzled
    const int tid = threadIdx.x, lane = tid & 63, wid = tid >> 6;
    const int u = lane & 15, q = lane >> 4;
    const int wm = wid & 1, wn = wid >> 1;
    const int m0 = blockIdx.x * 128, n0 = blockIdx.y * 128;
    const int arow = tid >> 1, acs = (tid & 1) * 2;
    const int swz = (arow >> 1) & 3;

    f32x4 acc[4][4];
    const f32x4 z = {0.f, 0.f, 0.f, 0.f};
    #pragma unroll
    for (int mi = 0; mi < 4; ++mi)
        #pragma unroll
        for (int ni = 0; ni < 4; ++ni) acc[mi][ni] = z;

    for (int k0 = 0; k0 < 512; k0 += 32) {
        uint4 av0 = *(const uint4*)(A  + (size_t)(m0 + arow) * 512 + k0 + acs * 8);
        uint4 av1 = *(const uint4*)(A  + (size_t)(m0 + arow) * 512 + k0 + acs * 8 + 8);
        uint4 bv0 = *(const uint4*)(Bw + (size_t)(n0 + arow) * 512 + k0 + acs * 8);
        uint4 bv1 = *(const uint4*)(Bw + (size_t)(n0 + arow) * 512 + k0 + acs * 8 + 8);
        __syncthreads();
        *(uint4*)&As[arow * 32 + (((acs + 0) ^ swz) << 3)] = av0;
        *(uint4*)&As[arow * 32 + (((acs + 1) ^ swz) << 3)] = av1;
        *(uint4*)&Bs[arow * 32 + (((acs + 0) ^ swz) << 3)] = bv0;
        *(uint4*)&Bs[arow * 32 + (((acs + 1) ^ swz) << 3)] = bv1;
        __syncthreads();
        const int rswz = (q ^ ((u >> 1) & 3)) << 3;
        bf16x8 af[4], bfr[4];
        #pragma unroll
        for (int mi = 0; mi < 4; ++mi)
            af[mi] = *(const bf16x8*)&As[(wm * 64 + mi * 16 + u) * 32 + rswz];
        #pragma unroll
        for (int ni = 0; ni < 4; ++ni)
            bfr[ni] = *(const bf16x8*)&Bs[(wn * 64 + ni * 16 + u) * 32 + rswz];
        #pragma unroll
        for (int mi = 0; mi < 4; ++mi)
            #pragma unroll
            for (int ni = 0; ni < 4; ++ni)
                acc[mi][ni] = __builtin_amdgcn_mfma_f32_16x16x32_bf16(
                    af[mi], bfr[ni], acc[mi][ni], 0, 0, 0);
    }
    if (n0 < 1024) {   // Q or K region -> qkvT natural [m][o]
        const float scl = (n0 < 512) ? SCALE2 : 1.0f;
        #pragma unroll
        for (int ni = 0; ni < 4; ++ni) {
            int o = n0 + wn * 64 + ni * 16 + u;
            float bv = bias[o];
            #pragma unroll
            for (int mi = 0; mi < 4; ++mi)
                #pragma unroll
                for (int r = 0; r < 4; ++r) {
                    int m = m0 + wm * 64 + mi * 16 + q * 4 + r;
                    out[(size_t)m * OC3 + o] = f2bf((acc[mi][ni][r] + bv) * scl);
                }
        }
    } else {           // V region -> Vn[b][h][d][t] (transposed), packed 8B
        #pragma unroll
        for (int ni = 0; ni < 4; ++ni) {
            int o = n0 + wn * 64 + ni * 16 + u;
            float bv = bias[o];
            int oo = o - 1024;
            int hv = oo >> 6, d = oo & 63;
            #pragma unroll
            for (int mi = 0; mi < 4; ++mi) {
                int m = m0 + wm * 64 + mi * 16 + q * 4;
                int b = m >> 11, t = m & 2047;
                uint2 w;
                w.x = pack2bf(acc[mi][ni][0] + bv, acc[mi][ni][1] + bv);
                w.y = pack2bf(acc[mi][ni][2] + bv, acc[mi][ni][3] + bv);
                *(uint2*)(Vn + ((size_t)((b * 8 + hv) * 64 + d)) * VN_STRIDE + t) = w;
            }
        }
    }
}

// ---------------------------------------------------------------------------
// Flash attention v11: exact R8 structure (batched per-round loads, barrier-
// free, register-resident P, native exp, R8 strides) with pointer state
// consolidated to 2 base pointers (+wave-uniform SGPR-foldable offsets) so
// unified regs ~164 <= 170 -> 3 waves/SIMD at (256,3) WITHOUT spill.
// ---------------------------------------------------------------------------
__global__ __launch_bounds__(256, 3)
void flash(const ushortT* __restrict__ qkvT, const ushortT* __restrict__ Vn,
           ushortT* __restrict__ AO)
{
    __shared__ __align__(16) ushortT lds[4 * 4608];   // epilogue Obuf only
    __shared__ float Lbuf[4][64];

    const int tid = threadIdx.x, lane = tid & 63, wid = tid >> 6;
    const int u = lane & 15, q = lane >> 4;
    // XCD swizzle: XCD k owns bh = 4k..4k+3
    const int gid = blockIdx.y * 32 + blockIdx.x;
    const int xg = gid >> 3;
    const int bh = (gid & 7) * 4 + (xg >> 5);
    const int tb = xg & 31;
    const int bb = bh >> 3, h = bh & 7;
    const int tblk = tb * 64;
    const size_t qbase = (size_t)bb * T_DIM * OC3;

    // Q B-frags (n=u -> t row, k=q*8+j contiguous), persistent: 64 t-rows
    bf16x8 qb[4][2];
    #pragma unroll
    for (int ti = 0; ti < 4; ++ti)
        #pragma unroll
        for (int kst = 0; kst < 2; ++kst)
            qb[ti][kst] = *(const bf16x8*)(qkvT + qbase
                + (size_t)(tblk + ti * 16 + u) * OC3 + h * 64 + kst * 32 + q * 8);

    // single K base (lane-variant u row + q chunk folded in); si/round offsets
    // are wave-uniform -> SGPR-folded by the compiler
    const ushortT* kbase = qkvT + qbase + (size_t)(wid * 512 + u) * OC3 + 512 + h * 64 + q * 8;
    // single V base (lane-variant u row + q offset folded in)
    const ushortT* vbase = Vn + ((size_t)bh * 64 + u) * VN_STRIDE + wid * 512 + q * 4;

    f32x4 acc[4][4];   // [ci][ti] : O^T[c][t], c = ci*16+q*4+r, t = ti*16+u
    const f32x4 z = {0.f, 0.f, 0.f, 0.f};
    #pragma unroll
    for (int ci = 0; ci < 4; ++ci)
        #pragma unroll
        for (int ti = 0; ti < 4; ++ti) acc[ci][ti] = z;
    float lpart[4] = {0.f, 0.f, 0.f, 0.f};

    for (int rnd = 0; rnd < 8; ++rnd) {
        // ---- issue ALL of this round's loads first (24 VMEM in flight) ----
        bf16x8 ka[4][2];
        #pragma unroll
        for (int si = 0; si < 4; ++si) {
            ka[si][0] = *(const bf16x8*)(kbase + (size_t)si * 16 * OC3);
            ka[si][1] = *(const bf16x8*)(kbase + (size_t)si * 16 * OC3 + 32);
        }
        bf16x4 va[4][4];
        #pragma unroll
        for (int si = 0; si < 4; ++si)
            #pragma unroll
            for (int ci = 0; ci < 4; ++ci)
                va[si][ci] = *(const bf16x4*)(vbase + (size_t)ci * 16 * VN_STRIDE + si * 16);

        #pragma unroll
        for (int si = 0; si < 4; ++si) {
            // --- S^T 16(s) x 64(t) slab ---
            f32x4 sacc[4] = {z, z, z, z};
            #pragma unroll
            for (int ti = 0; ti < 4; ++ti)
                sacc[ti] = __builtin_amdgcn_mfma_f32_16x16x32_bf16(
                    ka[si][0], qb[ti][0], sacc[ti], 0, 0, 0);
            #pragma unroll
            for (int ti = 0; ti < 4; ++ti)
                sacc[ti] = __builtin_amdgcn_mfma_f32_16x16x32_bf16(
                    ka[si][1], qb[ti][1], sacc[ti], 0, 0, 0);
            // --- raw v_exp_f32, pack, PV straight from registers (K=16) ---
            #pragma unroll
            for (int ti = 0; ti < 4; ++ti) {
                float p0 = __builtin_amdgcn_exp2f(sacc[ti][0]);
                float p1 = __builtin_amdgcn_exp2f(sacc[ti][1]);
                float p2 = __builtin_amdgcn_exp2f(sacc[ti][2]);
                float p3 = __builtin_amdgcn_exp2f(sacc[ti][3]);
                lpart[ti] += (p0 + p1) + (p2 + p3);
                union { uint2 u2; bf16x4 v; } pw;
                pw.u2.x = pack2bf(p0, p1);
                pw.u2.y = pack2bf(p2, p3);
                #pragma unroll
                for (int ci = 0; ci < 4; ++ci)
                    acc[ci][ti] = __builtin_amdgcn_mfma_f32_16x16x16bf16_1k(
                        va[si][ci], pw.v, acc[ci][ti], 0, 0, 0);
            }
        }
        kbase += 64 * OC3;
        vbase += 64;
    }

    // ---- 4-way s-stream merge ----
    #pragma unroll
    for (int ti = 0; ti < 4; ++ti) {
        float l = lpart[ti];
        l += __shfl_xor(l, 16);
        l += __shfl_xor(l, 32);
        lpart[ti] = l;
    }
    ushortT* Ob = lds + wid * 4608;   // [64t][72c] padded
    if (q == 0) {
        #pragma unroll
        for (int ti = 0; ti < 4; ++ti) Lbuf[wid][ti * 16 + u] = lpart[ti];
    }
    #pragma unroll
    for (int ci = 0; ci < 4; ++ci)
        #pragma unroll
        for (int ti = 0; ti < 4; ++ti) {
            uint2 w;
            w.x = pack2bf(acc[ci][ti][0], acc[ci][ti][1]);
            w.y = pack2bf(acc[ci][ti][2], acc[ci][ti][3]);
            *(uint2*)&Ob[(ti * 16 + u) * 72 + ci * 16 + q * 4] = w;
        }
    __syncthreads();
    {
        const int t = tid >> 2, cs = (tid & 3) * 16;
        float linv = 1.0f / (Lbuf[0][t] + Lbuf[1][t] + Lbuf[2][t] + Lbuf[3][t]);
        float vs[16];
        #pragma unroll
        for (int j = 0; j < 16; ++j) vs[j] = 0.f;
        #pragma unroll
        for (int w = 0; w < 4; ++w) {
            const ushortT* row = lds + w * 4608 + t * 72 + cs;
            #pragma unroll
            for (int j2 = 0; j2 < 2; ++j2) {
                uint4 rv = *(const uint4*)(row + j2 * 8);
                const uintT* rp = (const uintT*)&rv;
                #pragma unroll
                for (int k = 0; k < 4; ++k) {
                    vs[j2 * 8 + k * 2 + 0] += bf2f((ushortT)(rp[k] & 0xFFFF));
                    vs[j2 * 8 + k * 2 + 1] += bf2f((ushortT)(rp[k] >> 16));
                }
            }
        }
        uint4 o0, o1;
        uintT* op0 = (uintT*)&o0; uintT* op1 = (uintT*)&o1;
        #pragma unroll
        for (int k = 0; k < 4; ++k) {
            op0[k] = pack2bf(vs[k * 2] * linv, vs[k * 2 + 1] * linv);
            op1[k] = pack2bf(vs[8 + k * 2] * linv, vs[8 + k * 2 + 1] * linv);
        }
        size_t orow = ((size_t)bb * T_DIM + tblk + t) * C_DIM + h * 64 + cs;
        *(uint4*)(AO + orow) = o0;
        *(uint4*)(AO + orow + 8) = o1;
    }
}

// ---------------------------------------------------------------------------
// Proj GEMM: out[b][o][t] = sum_c Wp[o][c]*AO[(b,t)][c] + bias[o] + x[b][o][t]
// ---------------------------------------------------------------------------
__global__ __launch_bounds__(256, 2) void gemm_proj(const ushortT* __restrict__ Wp,
                                                    const ushortT* __restrict__ AOv,
                                                    const float* __restrict__ bias,
                                                    const float* __restrict__ xres,
                                                    float* __restrict__ out) {
    __shared__ ushortT As[4096], Bs[4096];
    const int tid = threadIdx.x, lane = tid & 63, wid = tid >> 6;
    const int u = lane & 15, q = lane >> 4;
    const int wm = wid & 1, wn = wid >> 1;
    const int m0 = blockIdx.y * 128, n0 = blockIdx.x * 128;
    const int arow = tid >> 1, acs = (tid & 1) * 2;
    const int swz = (arow >> 1) & 3;

    f32x4 acc[4][4];
    const f32x4 z = {0.f, 0.f, 0.f, 0.f};
    #pragma unroll
    for (int mi = 0; mi < 4; ++mi)
        #pragma unroll
        for (int ni = 0; ni < 4; ++ni) acc[mi][ni] = z;

    for (int k0 = 0; k0 < 512; k0 += 32) {
        uint4 av0 = *(const uint4*)(Wp  + (size_t)(m0 + arow) * 512 + k0 + acs * 8);
        uint4 av1 = *(const uint4*)(Wp  + (size_t)(m0 + arow) * 512 + k0 + acs * 8 + 8);
        uint4 bv0 = *(const uint4*)(AOv + (size_t)(n0 + arow) * 512 + k0 + acs * 8);
        uint4 bv1 = *(const uint4*)(AOv + (size_t)(n0 + arow) * 512 + k0 + acs * 8 + 8);
        __syncthreads();
        *(uint4*)&As[arow * 32 + (((acs + 0) ^ swz) << 3)] = av0;
        *(uint4*)&As[arow * 32 + (((acs + 1) ^ swz) << 3)] = av1;
        *(uint4*)&Bs[arow * 32 + (((acs + 0) ^ swz) << 3)] = bv0;
        *(uint4*)&Bs[arow * 32 + (((acs + 1) ^ swz) << 3)] = bv1;
        __syncthreads();
        const int rswz = (q ^ ((u >> 1) & 3)) << 3;
        bf16x8 af[4], bfr[4];
        #pragma unroll
        for (int mi = 0; mi < 4; ++mi)
            af[mi] = *(const bf16x8*)&As[(wm * 64 + mi * 16 + u) * 32 + rswz];
        #pragma unroll
        for (int ni = 0; ni < 4; ++ni)
            bfr[ni] = *(const bf16x8*)&Bs[(wn * 64 + ni * 16 + u) * 32 + rswz];
        #pragma unroll
        for (int mi = 0; mi < 4; ++mi)
            #pragma unroll
            for (int ni = 0; ni < 4; ++ni)
                acc[mi][ni] = __builtin_amdgcn_mfma_f32_16x16x32_bf16(
                    af[mi], bfr[ni], acc[mi][ni], 0, 0, 0);
    }
    #pragma unroll
    for (int mi = 0; mi < 4; ++mi)
        #pragma unroll
        for (int r = 0; r < 4; ++r) {
            int o = m0 + wm * 64 + mi * 16 + q * 4 + r;
            float bv = bias[o];
            #pragma unroll
            for (int ni = 0; ni < 4; ++ni) {
                int n = n0 + wn * 64 + ni * 16 + u;
                int b = n >> 11, t = n & 2047;
                size_t oi = ((size_t)b * C_DIM + o) * T_DIM + t;
                out[oi] = acc[mi][ni][r] + bv + xres[oi];
            }
        }
}

// ---------------------------------------------------------------------------
extern "C" void kernel_launch(void* const* d_in, const int* in_sizes, int n_in,
                              void* d_out, int out_size, void* d_ws, size_t ws_size,
                              hipStream_t stream)
{
    const float* x      = (const float*)d_in[0];
    const float* qkv_w  = (const float*)d_in[1];
    const float* qkv_b  = (const float*)d_in[2];
    const float* proj_w = (const float*)d_in[3];
    const float* proj_b = (const float*)d_in[4];
    float* out = (float*)d_out;

    char* ws = (char*)d_ws;
    ushortT* xb   = (ushortT*)(ws);                 //  8.39 MB  [8192][512]
    ushortT* wqb  = (ushortT*)(ws +  8388608);      //  1.57 MB  [1536][512]
    ushortT* wpb  = (ushortT*)(ws +  9961472);      //  0.52 MB  [512][512]
    ushortT* qkvT = (ushortT*)(ws + 10485760);      // 25.17 MB  [8192][1536] (V third unused)
    ushortT* Vn   = (ushortT*)(ws + 35651584);      //  8.45 MB  [4][8][64][VN_STRIDE]
    ushortT* AO   = (ushortT*)(ws + 44105728);      //  8.39 MB  [8192][512]

    prep     <<<2048, 256, 0, stream>>>(x, qkv_w, proj_w, xb, wqb, wpb);
    gemm_qkv <<<dim3(64, 12),   256, 0, stream>>>(xb, wqb, qkv_b, qkvT, Vn);
    flash    <<<dim3(32, 32),   256, 0, stream>>>(qkvT, Vn, AO);
    gemm_proj<<<dim3(64, 4),    256, 0, stream>>>(wpb, AO, proj_b, x, out);
}

// Round 12
// 181.487 us; speedup vs baseline: 1.4928x; 1.4928x over previous
//
#include <hip/hip_runtime.h>
#include <hip/hip_bf16.h>
#include <math.h>

#define B_DIM 4
#define C_DIM 512
#define T_DIM 2048
#define H_DIM 8
#define OC3   1536
#define VN_STRIDE 2064   // R8-measured-best (R10 de-alias experiment regressed)
#define SCALE 0.044194173824159216f   // 512^-0.5 (full C, per reference)
#define SCALE2 (0.044194173824159216f * 1.4426950408889634f)   // fold log2(e)

typedef unsigned short ushortT;
typedef unsigned int uintT;
typedef __attribute__((ext_vector_type(8))) short bf16x8;
typedef __attribute__((ext_vector_type(4))) short bf16x4;
typedef __attribute__((ext_vector_type(4))) float f32x4;

__device__ __forceinline__ ushortT f2bf(float f) {
    union { float f; uintT u; } v; v.f = f;
    uintT r = v.u + 0x7FFF + ((v.u >> 16) & 1);   // RNE
    return (ushortT)(r >> 16);
}
__device__ __forceinline__ float bf2f(ushortT h) {
    union { uintT u; float f; } v; v.u = ((uintT)h) << 16;
    return v.f;
}
__device__ __forceinline__ uintT pack2bf(float a, float b) {
    uintT ua = __float_as_uint(a) + 0x8000u;
    uintT ub = __float_as_uint(b) + 0x8000u;
    return (ua >> 16) | (ub & 0xFFFF0000u);
}
// async global->LDS, 16B per lane; lds base must be wave-uniform (data lands
// at base + lane*16) [m97/m104]
__device__ __forceinline__ void gload_lds16(const ushortT* g, ushortT* l) {
    __builtin_amdgcn_global_load_lds(
        (const __attribute__((address_space(1))) void*)g,
        (__attribute__((address_space(3))) void*)l, 16, 0, 0);
}

// ---------------------------------------------------------------------------
// prep: fused conv_x (blocks 0..1023) + conv_w (blocks 1024..2047).
// ---------------------------------------------------------------------------
__global__ __launch_bounds__(256) void prep(const float* __restrict__ x,
                                            const float* __restrict__ qw,
                                            const float* __restrict__ pw,
                                            ushortT* __restrict__ xb,
                                            ushortT* __restrict__ qwb,
                                            ushortT* __restrict__ pwb) {
    __shared__ float xs[64][65];
    const int tid = threadIdx.x;
    const int blk = blockIdx.x;
    if (blk >= 1024) {
        int idx = ((blk - 1024) * 256 + tid) * 4;
        if (idx < OC3 * C_DIM) {
            float4 v = *(const float4*)(qw + idx);
            qwb[idx + 0] = f2bf(v.x); qwb[idx + 1] = f2bf(v.y);
            qwb[idx + 2] = f2bf(v.z); qwb[idx + 3] = f2bf(v.w);
        } else {
            idx -= OC3 * C_DIM;
            float4 v = *(const float4*)(pw + idx);
            pwb[idx + 0] = f2bf(v.x); pwb[idx + 1] = f2bf(v.y);
            pwb[idx + 2] = f2bf(v.z); pwb[idx + 3] = f2bf(v.w);
        }
        return;
    }
    const int b = blk >> 8, rem = blk & 255;
    const int c0 = (rem >> 5) * 64, t0 = (rem & 31) * 64;
    #pragma unroll
    for (int it = 0; it < 4; ++it) {
        int idx = it * 256 + tid;
        int r = idx >> 4, ch = idx & 15;
        float4 v = *(const float4*)(x + ((size_t)(b * C_DIM + c0 + r)) * T_DIM + t0 + ch * 4);
        xs[r][ch * 4 + 0] = v.x; xs[r][ch * 4 + 1] = v.y;
        xs[r][ch * 4 + 2] = v.z; xs[r][ch * 4 + 3] = v.w;
    }
    __syncthreads();
    #pragma unroll
    for (int it = 0; it < 2; ++it) {
        int idx = it * 256 + tid;
        int rt = idx >> 3, ch = idx & 7;
        union { ushortT s[8]; uint4 v; } tmp;
        #pragma unroll
        for (int k = 0; k < 8; ++k) tmp.s[k] = f2bf(xs[ch * 8 + k][rt]);
        *(uint4*)(xb + ((size_t)b * T_DIM + t0 + rt) * C_DIM + c0 + ch * 8) = tmp.v;
    }
}

// ---------------------------------------------------------------------------
// QKV GEMM with m97-style async staging: global_load_lds width=16, linear
// LDS [row][32] (8KB per operand). qkvT[m][o] = xb[m][:]·W[o][:] + bias;
// Q pre-scaled; V region written transposed into Vn.
// ---------------------------------------------------------------------------
__global__ __launch_bounds__(256, 2) void gemm_qkv(const ushortT* __restrict__ A,
                                                   const ushortT* __restrict__ Bw,
                                                   const float* __restrict__ bias,
                                                   ushortT* __restrict__ out,
                                                   ushortT* __restrict__ Vn) {
    __shared__ __align__(16) ushortT As[4096], Bs[4096];   // [128][32] linear
    const int tid = threadIdx.x, lane = tid & 63, wid = tid >> 6;
    const int u = lane & 15, q = lane >> 4;
    const int wm = wid & 1, wn = wid >> 1;
    const int m0 = blockIdx.x * 128, n0 = blockIdx.y * 128;
    const int lrow = lane >> 2, lcol = (lane & 3) * 8;

    f32x4 acc[4][4];
    const f32x4 z = {0.f, 0.f, 0.f, 0.f};
    #pragma unroll
    for (int mi = 0; mi < 4; ++mi)
        #pragma unroll
        for (int ni = 0; ni < 4; ++ni) acc[mi][ni] = z;

    for (int k0 = 0; k0 < 512; k0 += 32) {
        __syncthreads();   // prior reads done before overwrite
        gload_lds16(A  + (size_t)(m0 + wid * 32 +      lrow) * 512 + k0 + lcol, &As[(wid * 32     ) * 32]);
        gload_lds16(A  + (size_t)(m0 + wid * 32 + 16 + lrow) * 512 + k0 + lcol, &As[(wid * 32 + 16) * 32]);
        gload_lds16(Bw + (size_t)(n0 + wid * 32 +      lrow) * 512 + k0 + lcol, &Bs[(wid * 32     ) * 32]);
        gload_lds16(Bw + (size_t)(n0 + wid * 32 + 16 + lrow) * 512 + k0 + lcol, &Bs[(wid * 32 + 16) * 32]);
        __syncthreads();   // vmcnt drained by barrier -> data visible
        bf16x8 af[4], bfr[4];
        #pragma unroll
        for (int mi = 0; mi < 4; ++mi)
            af[mi] = *(const bf16x8*)&As[(wm * 64 + mi * 16 + u) * 32 + q * 8];
        #pragma unroll
        for (int ni = 0; ni < 4; ++ni)
            bfr[ni] = *(const bf16x8*)&Bs[(wn * 64 + ni * 16 + u) * 32 + q * 8];
        #pragma unroll
        for (int mi = 0; mi < 4; ++mi)
            #pragma unroll
            for (int ni = 0; ni < 4; ++ni)
                acc[mi][ni] = __builtin_amdgcn_mfma_f32_16x16x32_bf16(
                    af[mi], bfr[ni], acc[mi][ni], 0, 0, 0);
    }
    if (n0 < 1024) {   // Q or K region -> qkvT natural [m][o]
        const float scl = (n0 < 512) ? SCALE2 : 1.0f;
        #pragma unroll
        for (int ni = 0; ni < 4; ++ni) {
            int o = n0 + wn * 64 + ni * 16 + u;
            float bv = bias[o];
            #pragma unroll
            for (int mi = 0; mi < 4; ++mi)
                #pragma unroll
                for (int r = 0; r < 4; ++r) {
                    int m = m0 + wm * 64 + mi * 16 + q * 4 + r;
                    out[(size_t)m * OC3 + o] = f2bf((acc[mi][ni][r] + bv) * scl);
                }
        }
    } else {           // V region -> Vn[b][h][d][t] (transposed), packed 8B
        #pragma unroll
        for (int ni = 0; ni < 4; ++ni) {
            int o = n0 + wn * 64 + ni * 16 + u;
            float bv = bias[o];
            int oo = o - 1024;
            int hv = oo >> 6, d = oo & 63;
            #pragma unroll
            for (int mi = 0; mi < 4; ++mi) {
                int m = m0 + wm * 64 + mi * 16 + q * 4;
                int b = m >> 11, t = m & 2047;
                uint2 w;
                w.x = pack2bf(acc[mi][ni][0] + bv, acc[mi][ni][1] + bv);
                w.y = pack2bf(acc[mi][ni][2] + bv, acc[mi][ni][3] + bv);
                *(uint2*)(Vn + ((size_t)((b * 8 + hv) * 64 + d)) * VN_STRIDE + t) = w;
            }
        }
    }
}

// ---------------------------------------------------------------------------
// Flash attention: EXACT R8 structure (measured 76 us, VGPR 108, no spill).
// Batched per-round loads, barrier-free, register-resident P, native exp.
// ---------------------------------------------------------------------------
__global__ __launch_bounds__(256, 2)
void flash(const ushortT* __restrict__ qkvT, const ushortT* __restrict__ Vn,
           ushortT* __restrict__ AO)
{
    __shared__ __align__(16) ushortT lds[4 * 4608];   // epilogue Obuf only
    __shared__ float Lbuf[4][64];

    const int tid = threadIdx.x, lane = tid & 63, wid = tid >> 6;
    const int u = lane & 15, q = lane >> 4;
    const int gid = blockIdx.y * 32 + blockIdx.x;
    const int xg = gid >> 3;
    const int bh = (gid & 7) * 4 + (xg >> 5);
    const int tb = xg & 31;
    const int bb = bh >> 3, h = bh & 7;
    const int tblk = tb * 64;
    const size_t qbase = (size_t)bb * T_DIM * OC3;

    bf16x8 qb[4][2];
    #pragma unroll
    for (int ti = 0; ti < 4; ++ti)
        #pragma unroll
        for (int kst = 0; kst < 2; ++kst)
            qb[ti][kst] = *(const bf16x8*)(qkvT + qbase
                + (size_t)(tblk + ti * 16 + u) * OC3 + h * 64 + kst * 32 + q * 8);

    const ushortT* kp[4];
    #pragma unroll
    for (int si = 0; si < 4; ++si)
        kp[si] = qkvT + qbase + (size_t)(wid * 512 + si * 16 + u) * OC3 + 512 + h * 64;
    const ushortT* vp[4];
    #pragma unroll
    for (int ci = 0; ci < 4; ++ci)
        vp[ci] = Vn + ((size_t)bh * 64 + ci * 16 + u) * VN_STRIDE + wid * 512 + q * 4;

    f32x4 acc[4][4];
    const f32x4 z = {0.f, 0.f, 0.f, 0.f};
    #pragma unroll
    for (int ci = 0; ci < 4; ++ci)
        #pragma unroll
        for (int ti = 0; ti < 4; ++ti) acc[ci][ti] = z;
    float lpart[4] = {0.f, 0.f, 0.f, 0.f};

    for (int rnd = 0; rnd < 8; ++rnd) {
        bf16x8 ka[4][2];
        #pragma unroll
        for (int si = 0; si < 4; ++si) {
            ka[si][0] = *(const bf16x8*)(kp[si] + q * 8);
            ka[si][1] = *(const bf16x8*)(kp[si] + 32 + q * 8);
        }
        bf16x4 va[4][4];
        #pragma unroll
        for (int si = 0; si < 4; ++si)
            #pragma unroll
            for (int ci = 0; ci < 4; ++ci)
                va[si][ci] = *(const bf16x4*)(vp[ci] + si * 16);

        #pragma unroll
        for (int si = 0; si < 4; ++si) {
            f32x4 sacc[4] = {z, z, z, z};
            #pragma unroll
            for (int ti = 0; ti < 4; ++ti)
                sacc[ti] = __builtin_amdgcn_mfma_f32_16x16x32_bf16(
                    ka[si][0], qb[ti][0], sacc[ti], 0, 0, 0);
            #pragma unroll
            for (int ti = 0; ti < 4; ++ti)
                sacc[ti] = __builtin_amdgcn_mfma_f32_16x16x32_bf16(
                    ka[si][1], qb[ti][1], sacc[ti], 0, 0, 0);
            #pragma unroll
            for (int ti = 0; ti < 4; ++ti) {
                float p0 = __builtin_amdgcn_exp2f(sacc[ti][0]);
                float p1 = __builtin_amdgcn_exp2f(sacc[ti][1]);
                float p2 = __builtin_amdgcn_exp2f(sacc[ti][2]);
                float p3 = __builtin_amdgcn_exp2f(sacc[ti][3]);
                lpart[ti] += (p0 + p1) + (p2 + p3);
                union { uint2 u2; bf16x4 v; } pw;
                pw.u2.x = pack2bf(p0, p1);
                pw.u2.y = pack2bf(p2, p3);
                #pragma unroll
                for (int ci = 0; ci < 4; ++ci)
                    acc[ci][ti] = __builtin_amdgcn_mfma_f32_16x16x16bf16_1k(
                        va[si][ci], pw.v, acc[ci][ti], 0, 0, 0);
            }
        }
        #pragma unroll
        for (int si = 0; si < 4; ++si) kp[si] += 64 * OC3;
        #pragma unroll
        for (int ci = 0; ci < 4; ++ci) vp[ci] += 64;
    }

    #pragma unroll
    for (int ti = 0; ti < 4; ++ti) {
        float l = lpart[ti];
        l += __shfl_xor(l, 16);
        l += __shfl_xor(l, 32);
        lpart[ti] = l;
    }
    ushortT* Ob = lds + wid * 4608;
    if (q == 0) {
        #pragma unroll
        for (int ti = 0; ti < 4; ++ti) Lbuf[wid][ti * 16 + u] = lpart[ti];
    }
    #pragma unroll
    for (int ci = 0; ci < 4; ++ci)
        #pragma unroll
        for (int ti = 0; ti < 4; ++ti) {
            uint2 w;
            w.x = pack2bf(acc[ci][ti][0], acc[ci][ti][1]);
            w.y = pack2bf(acc[ci][ti][2], acc[ci][ti][3]);
            *(uint2*)&Ob[(ti * 16 + u) * 72 + ci * 16 + q * 4] = w;
        }
    __syncthreads();
    {
        const int t = tid >> 2, cs = (tid & 3) * 16;
        float linv = 1.0f / (Lbuf[0][t] + Lbuf[1][t] + Lbuf[2][t] + Lbuf[3][t]);
        float vs[16];
        #pragma unroll
        for (int j = 0; j < 16; ++j) vs[j] = 0.f;
        #pragma unroll
        for (int w = 0; w < 4; ++w) {
            const ushortT* row = lds + w * 4608 + t * 72 + cs;
            #pragma unroll
            for (int j2 = 0; j2 < 2; ++j2) {
                uint4 rv = *(const uint4*)(row + j2 * 8);
                const uintT* rp = (const uintT*)&rv;
                #pragma unroll
                for (int k = 0; k < 4; ++k) {
                    vs[j2 * 8 + k * 2 + 0] += bf2f((ushortT)(rp[k] & 0xFFFF));
                    vs[j2 * 8 + k * 2 + 1] += bf2f((ushortT)(rp[k] >> 16));
                }
            }
        }
        uint4 o0, o1;
        uintT* op0 = (uintT*)&o0; uintT* op1 = (uintT*)&o1;
        #pragma unroll
        for (int k = 0; k < 4; ++k) {
            op0[k] = pack2bf(vs[k * 2] * linv, vs[k * 2 + 1] * linv);
            op1[k] = pack2bf(vs[8 + k * 2] * linv, vs[8 + k * 2 + 1] * linv);
        }
        size_t orow = ((size_t)bb * T_DIM + tblk + t) * C_DIM + h * 64 + cs;
        *(uint4*)(AO + orow) = o0;
        *(uint4*)(AO + orow + 8) = o1;
    }
}

// ---------------------------------------------------------------------------
// Proj GEMM with async staging: out = Wp·AO^T + bias + x (fp32 out).
// ---------------------------------------------------------------------------
__global__ __launch_bounds__(256, 2) void gemm_proj(const ushortT* __restrict__ Wp,
                                                    const ushortT* __restrict__ AOv,
                                                    const float* __restrict__ bias,
                                                    const float* __restrict__ xres,
                                                    float* __restrict__ out) {
    __shared__ __align__(16) ushortT As[4096], Bs[4096];   // [128][32] linear
    const int tid = threadIdx.x, lane = tid & 63, wid = tid >> 6;
    const int u = lane & 15, q = lane >> 4;
    const int wm = wid & 1, wn = wid >> 1;
    const int m0 = blockIdx.y * 128, n0 = blockIdx.x * 128;
    const int lrow = lane >> 2, lcol = (lane & 3) * 8;

    f32x4 acc[4][4];
    const f32x4 z = {0.f, 0.f, 0.f, 0.f};
    #pragma unroll
    for (int mi = 0; mi < 4; ++mi)
        #pragma unroll
        for (int ni = 0; ni < 4; ++ni) acc[mi][ni] = z;

    for (int k0 = 0; k0 < 512; k0 += 32) {
        __syncthreads();
        gload_lds16(Wp  + (size_t)(m0 + wid * 32 +      lrow) * 512 + k0 + lcol, &As[(wid * 32     ) * 32]);
        gload_lds16(Wp  + (size_t)(m0 + wid * 32 + 16 + lrow) * 512 + k0 + lcol, &As[(wid * 32 + 16) * 32]);
        gload_lds16(AOv + (size_t)(n0 + wid * 32 +      lrow) * 512 + k0 + lcol, &Bs[(wid * 32     ) * 32]);
        gload_lds16(AOv + (size_t)(n0 + wid * 32 + 16 + lrow) * 512 + k0 + lcol, &Bs[(wid * 32 + 16) * 32]);
        __syncthreads();
        bf16x8 af[4], bfr[4];
        #pragma unroll
        for (int mi = 0; mi < 4; ++mi)
            af[mi] = *(const bf16x8*)&As[(wm * 64 + mi * 16 + u) * 32 + q * 8];
        #pragma unroll
        for (int ni = 0; ni < 4; ++ni)
            bfr[ni] = *(const bf16x8*)&Bs[(wn * 64 + ni * 16 + u) * 32 + q * 8];
        #pragma unroll
        for (int mi = 0; mi < 4; ++mi)
            #pragma unroll
            for (int ni = 0; ni < 4; ++ni)
                acc[mi][ni] = __builtin_amdgcn_mfma_f32_16x16x32_bf16(
                    af[mi], bfr[ni], acc[mi][ni], 0, 0, 0);
    }
    #pragma unroll
    for (int mi = 0; mi < 4; ++mi)
        #pragma unroll
        for (int r = 0; r < 4; ++r) {
            int o = m0 + wm * 64 + mi * 16 + q * 4 + r;
            float bv = bias[o];
            #pragma unroll
            for (int ni = 0; ni < 4; ++ni) {
                int n = n0 + wn * 64 + ni * 16 + u;
                int b = n >> 11, t = n & 2047;
                size_t oi = ((size_t)b * C_DIM + o) * T_DIM + t;
                out[oi] = acc[mi][ni][r] + bv + xres[oi];
            }
        }
}

// ---------------------------------------------------------------------------
extern "C" void kernel_launch(void* const* d_in, const int* in_sizes, int n_in,
                              void* d_out, int out_size, void* d_ws, size_t ws_size,
                              hipStream_t stream)
{
    const float* x      = (const float*)d_in[0];
    const float* qkv_w  = (const float*)d_in[1];
    const float* qkv_b  = (const float*)d_in[2];
    const float* proj_w = (const float*)d_in[3];
    const float* proj_b = (const float*)d_in[4];
    float* out = (float*)d_out;

    char* ws = (char*)d_ws;
    ushortT* xb   = (ushortT*)(ws);                 //  8.39 MB  [8192][512]
    ushortT* wqb  = (ushortT*)(ws +  8388608);      //  1.57 MB  [1536][512]
    ushortT* wpb  = (ushortT*)(ws +  9961472);      //  0.52 MB  [512][512]
    ushortT* qkvT = (ushortT*)(ws + 10485760);      // 25.17 MB  [8192][1536] (V third unused)
    ushortT* Vn   = (ushortT*)(ws + 35651584);      //  8.45 MB  [4][8][64][VN_STRIDE]
    ushortT* AO   = (ushortT*)(ws + 44105728);      //  8.39 MB  [8192][512]

    prep     <<<2048, 256, 0, stream>>>(x, qkv_w, proj_w, xb, wqb, wpb);
    gemm_qkv <<<dim3(64, 12),   256, 0, stream>>>(xb, wqb, qkv_b, qkvT, Vn);
    flash    <<<dim3(32, 32),   256, 0, stream>>>(qkvT, Vn, AO);
    gemm_proj<<<dim3(64, 4),    256, 0, stream>>>(wpb, AO, proj_b, x, out);
}